// Round 1
// baseline (663.584 us; speedup 1.0000x reference)
//
#include <hip/hip_runtime.h>
#include <math.h>

#define BN 16
#define SN 8192
#define DN 256
#define TS 32
#define DK 8
#define EPSF 1e-8f

// ---------------------------------------------------------------------------
// k1: fused q/k projection + neighbor-similarity + gates -> boundary_probs,
//     hard flags. One block = 32 sequence positions of one batch.
//     LDS: x (33 rows, transposed, stride 36 for 16B-aligned b128 reads),
//          Wq/Wk staged in DK=8-row chunks, w_vol/w_volu whole.
//     Thread (tx,ty): 4 rows x 8 cols register tile for BOTH q and k.
// ---------------------------------------------------------------------------
__global__ __launch_bounds__(256, 2) void k1_scores(
    const float* __restrict__ x,
    const float* __restrict__ Wq, const float* __restrict__ bq,
    const float* __restrict__ Wk, const float* __restrict__ bk,
    const float* __restrict__ w_vol, const float* __restrict__ b_vol,
    const float* __restrict__ w_volu, const float* __restrict__ b_volu,
    float* __restrict__ bp_out, int* __restrict__ flags)
{
    __shared__ float x_t[DN][TS + 4];   // [d][r], r = 0..32 <-> seq pos s0-1+r
    __shared__ float wq_s[DK][DN];
    __shared__ float wk_s[DK][DN];
    __shared__ float wv_s[DN];
    __shared__ float wu_s[DN];

    const int tid = threadIdx.x;
    const int tx  = tid & 31;
    const int ty  = tid >> 5;
    const int j0  = tx * 8;
    const int r0  = ty * 4;
    const int b   = blockIdx.y;
    const int s0  = blockIdx.x * TS;

    // stage x rows s0-1 .. s0+31, transposed (thread tid owns dim d = tid)
    {
        const size_t rowbase = (size_t)b * SN;
        #pragma unroll 4
        for (int r = 0; r < TS + 1; ++r) {
            int g = s0 - 1 + r;
            float v = (g >= 0) ? x[(rowbase + g) * DN + tid] : 0.0f;
            x_t[tid][r] = v;
        }
        wv_s[tid] = w_vol[tid];
        wu_s[tid] = w_volu[tid];
    }

    float qa[4][8], ka[4][8], vl[4], vu[4];
    #pragma unroll
    for (int i = 0; i < 4; ++i) {
        vl[i] = 0.f; vu[i] = 0.f;
        #pragma unroll
        for (int c = 0; c < 8; ++c) { qa[i][c] = 0.f; ka[i][c] = 0.f; }
    }

    const float4* Wq4 = (const float4*)Wq;
    const float4* Wk4 = (const float4*)Wk;
    float4* wq4 = (float4*)&wq_s[0][0];
    float4* wk4 = (float4*)&wk_s[0][0];

    for (int d0 = 0; d0 < DN; d0 += DK) {
        __syncthreads();   // protect LDS chunk reuse
        #pragma unroll
        for (int i = 0; i < (DK * DN / 4) / 256; ++i) {   // 2 float4 per thread
            int f = i * 256 + tid;
            int row = f >> 6, c = f & 63;
            wq4[f] = Wq4[(size_t)(d0 + row) * (DN / 4) + c];
            wk4[f] = Wk4[(size_t)(d0 + row) * (DN / 4) + c];
        }
        __syncthreads();

        #pragma unroll 4
        for (int dd = 0; dd < DK; ++dd) {
            const int d = d0 + dd;
            const float4 xv = *(const float4*)&x_t[d][r0];  // K rows r0..r0+3
            const float  xe = x_t[d][r0 + 4];               // extra for Q rows
            const float wvd = wv_s[d];
            const float wud = wu_s[d];
            const float4 wqa4 = *(const float4*)&wq_s[dd][j0];
            const float4 wqb4 = *(const float4*)&wq_s[dd][j0 + 4];
            const float4 wka4 = *(const float4*)&wk_s[dd][j0];
            const float4 wkb4 = *(const float4*)&wk_s[dd][j0 + 4];
            const float wq[8] = {wqa4.x, wqa4.y, wqa4.z, wqa4.w,
                                 wqb4.x, wqb4.y, wqb4.z, wqb4.w};
            const float wk[8] = {wka4.x, wka4.y, wka4.z, wka4.w,
                                 wkb4.x, wkb4.y, wkb4.z, wkb4.w};
            const float xk[4] = {xv.x, xv.y, xv.z, xv.w};   // seq s0-1+r0+i
            const float xq[4] = {xv.y, xv.z, xv.w, xe};     // seq s0+r0+i
            #pragma unroll
            for (int i = 0; i < 4; ++i) {
                #pragma unroll
                for (int c = 0; c < 8; ++c) {
                    qa[i][c] = fmaf(xq[i], wq[c], qa[i][c]);
                    ka[i][c] = fmaf(xk[i], wk[c], ka[i][c]);
                }
                vl[i] = fmaf(xq[i], wvd, vl[i]);
                vu[i] = fmaf(xq[i], wud, vu[i]);
            }
        }
    }

    // add biases
    {
        const float4 bqa = *(const float4*)&bq[j0];
        const float4 bqb = *(const float4*)&bq[j0 + 4];
        const float4 bka = *(const float4*)&bk[j0];
        const float4 bkb = *(const float4*)&bk[j0 + 4];
        const float bqv[8] = {bqa.x, bqa.y, bqa.z, bqa.w, bqb.x, bqb.y, bqb.z, bqb.w};
        const float bkv[8] = {bka.x, bka.y, bka.z, bka.w, bkb.x, bkb.y, bkb.z, bkb.w};
        #pragma unroll
        for (int i = 0; i < 4; ++i) {
            #pragma unroll
            for (int c = 0; c < 8; ++c) {
                qa[i][c] += bqv[c];
                ka[i][c] += bkv[c];
            }
        }
    }

    const float bvol0  = b_vol[0];
    const float bvolu0 = b_volu[0];

    #pragma unroll
    for (int i = 0; i < 4; ++i) {
        float dt = 0.f, nq = 0.f, nk = 0.f;
        #pragma unroll
        for (int c = 0; c < 8; ++c) {
            dt = fmaf(qa[i][c], ka[i][c], dt);
            nq = fmaf(qa[i][c], qa[i][c], nq);
            nk = fmaf(ka[i][c], ka[i][c], nk);
        }
        #pragma unroll
        for (int m = 1; m < 32; m <<= 1) {
            dt += __shfl_xor(dt, m);
            nq += __shfl_xor(nq, m);
            nk += __shfl_xor(nk, m);
        }
        if (tx == 0) {
            const int s = s0 + r0 + i;
            float comb;
            if (s == 0) {
                comb = 1.0f;
            } else {
                float denom = fmaxf(sqrtf(nq), EPSF) * fmaxf(sqrtf(nk), EPSF);
                float sim   = dt / denom;
                float vol   = 1.f / (1.f + expf(-(vl[i] + bvol0)));
                float volu  = 1.f / (1.f + expf(-(vu[i] + bvolu0)));
                comb = (1.0f - sim) + 0.3f * vol + 0.2f * volu;
            }
            float p = 1.f / (1.f + expf(-comb));
            size_t o = (size_t)b * SN + s;
            bp_out[o] = p;
            flags[o]  = (p > 0.5f) ? 1 : 0;
        }
    }
}

// ---------------------------------------------------------------------------
// k2: per-batch inclusive scan of hard flags -> packed dest index (or -1),
//     per-batch count, per-batch sum of boundaries (hard + bp - bp).
// ---------------------------------------------------------------------------
__global__ void k2_scan(const int* __restrict__ flags,
                        const float* __restrict__ bp,
                        int* __restrict__ pidx,
                        int* __restrict__ cnt,
                        float* __restrict__ bsum)
{
    const int b = blockIdx.x;
    const int t = threadIdx.x;
    __shared__ int   ssum[256];
    __shared__ float sf[256];

    const size_t base = (size_t)b * SN + (size_t)t * 32;
    int f[32];
    int run = 0;
    float fs = 0.f;
    #pragma unroll
    for (int i = 0; i < 32; ++i) {
        f[i] = flags[base + i];
        run += f[i];
        float p  = bp[base + i];
        float hf = (float)f[i];
        fs += hf + p - p;   // replicate straight-through trick numerics
    }
    ssum[t] = run;
    sf[t]   = fs;
    __syncthreads();

    // Hillis-Steele inclusive scan over 256 partials
    for (int off = 1; off < 256; off <<= 1) {
        int v = (t >= off) ? ssum[t - off] : 0;
        __syncthreads();
        ssum[t] += v;
        __syncthreads();
    }
    const int incl = ssum[t];
    int running = incl - run;   // exclusive prefix
    #pragma unroll
    for (int i = 0; i < 32; ++i) {
        running += f[i];
        pidx[base + i] = f[i] ? (running - 1) : -1;
    }
    if (t == 255) cnt[b] = incl;

    // reduce boundary sums
    for (int off = 128; off > 0; off >>= 1) {
        if (t < off) sf[t] += sf[t + off];
        __syncthreads();
    }
    if (t == 0) bsum[b] = sf[0];
}

// ---------------------------------------------------------------------------
// k3: gather-copy — each hard source row to its unique destination row.
// ---------------------------------------------------------------------------
__global__ void k3_scatter(const float* __restrict__ x,
                           const int* __restrict__ pidx,
                           float* __restrict__ out_comp)
{
    const int row = blockIdx.x;            // b*SN + s
    const int p   = pidx[row];
    if (p < 0) return;
    const int b = row / SN;
    const float4* src = (const float4*)(x + (size_t)row * DN);
    float4* dst = (float4*)(out_comp + ((size_t)b * SN + p) * DN);
    dst[threadIdx.x] = src[threadIdx.x];   // 64 threads x 16B = 1KB row
}

// k3b: zero destination rows beyond each batch's boundary count
__global__ void k3b_zerotail(float* __restrict__ out_comp,
                             const int* __restrict__ cnt)
{
    const int gid = blockIdx.x * blockDim.x + threadIdx.x;
    const int b = gid / SN;
    const int j = gid % SN;
    if (j >= cnt[b]) {
        float4* dst = (float4*)(out_comp + ((size_t)b * SN + j) * DN);
        const float4 z = make_float4(0.f, 0.f, 0.f, 0.f);
        for (int i = 0; i < DN / 4; ++i) dst[i] = z;
    }
}

// k4: ratio loss
__global__ void k4_loss(const float* __restrict__ bsum, float* __restrict__ out_rl)
{
    if (threadIdx.x == 0) {
        float acc = 0.f;
        for (int i = 0; i < BN; ++i) acc += bsum[i];
        float mean = acc / (float)BN;
        float d = mean - (float)(SN / 4);
        out_rl[0] = d * d;
    }
}

extern "C" void kernel_launch(void* const* d_in, const int* in_sizes, int n_in,
                              void* d_out, int out_size, void* d_ws, size_t ws_size,
                              hipStream_t stream) {
    const float* x      = (const float*)d_in[0];
    const float* Wq     = (const float*)d_in[1];
    const float* bq     = (const float*)d_in[2];
    const float* Wk     = (const float*)d_in[3];
    const float* bk     = (const float*)d_in[4];
    const float* w_vol  = (const float*)d_in[5];
    const float* b_vol  = (const float*)d_in[6];
    const float* w_volu = (const float*)d_in[7];
    const float* b_volu = (const float*)d_in[8];

    float* out_comp = (float*)d_out;                       // B*S*D
    float* out_bp   = out_comp + (size_t)BN * SN * DN;     // B*S
    float* out_rl   = out_bp + (size_t)BN * SN;            // 1

    int*   flags = (int*)d_ws;                             // B*S
    int*   pidx  = flags + (size_t)BN * SN;                // B*S
    int*   cnt   = pidx + (size_t)BN * SN;                 // B
    float* bsum  = (float*)(cnt + BN);                     // B

    k1_scores<<<dim3(SN / TS, BN), 256, 0, stream>>>(
        x, Wq, bq, Wk, bk, w_vol, b_vol, w_volu, b_volu, out_bp, flags);

    k2_scan<<<BN, 256, 0, stream>>>(flags, out_bp, pidx, cnt, bsum);

    k3_scatter<<<BN * SN, 64, 0, stream>>>(x, pidx, out_comp);

    k3b_zerotail<<<(BN * SN) / 256, 256, 0, stream>>>(out_comp, cnt);

    k4_loss<<<1, 64, 0, stream>>>(bsum, out_rl);
}

// Round 2
// 210.039 us; speedup vs baseline: 3.1593x; 3.1593x over previous
//
#include <hip/hip_runtime.h>
#include <math.h>

#define BN 16
#define SN 8192
#define DN 256
#define EPSF 1e-8f

#define XROWS 129
#define LDX 264          // padded LDS row stride in bf16 elems (528 B, 16B-aligned)
#define MBLK 128

typedef __attribute__((ext_vector_type(8))) short short8;
typedef __attribute__((ext_vector_type(4))) float f32x4;

__device__ __forceinline__ unsigned short f2bf(float f) {
    union { float f; unsigned int u; } cv; cv.f = f;
    unsigned int u = cv.u + 0x7FFFu + ((cv.u >> 16) & 1u);
    return (unsigned short)(u >> 16);
}

// ---------------------------------------------------------------------------
// k0: pre-transpose + bf16-convert weights: WT[n][k] = bf16(W[k][n])
// ---------------------------------------------------------------------------
__global__ void k0_prep(const float* __restrict__ Wq, const float* __restrict__ Wk,
                        unsigned short* __restrict__ WqT, unsigned short* __restrict__ WkT)
{
    const int n = blockIdx.x;
    const int k = threadIdx.x;
    WqT[(size_t)n * DN + k] = f2bf(Wq[(size_t)k * DN + n]);
    WkT[(size_t)n * DN + k] = f2bf(Wk[(size_t)k * DN + n]);
}

// ---------------------------------------------------------------------------
// k1: MFMA q/k projection + neighbor similarity + gates.
// Block: 256 threads (4 waves), 128 seq rows. x tile (129 rows halo) bf16 in
// LDS; W staged per 64-dim N-pass. Wave wm owns rows wm*32..+31 (2 M-frags),
// all 4 N-chunks of the pass. Gates via extra MFMA (pass 0, B cols 0/1).
// ---------------------------------------------------------------------------
extern "C" __global__ __launch_bounds__(256, 1) void k1_mfma(
    const float* __restrict__ x,
    const unsigned short* __restrict__ WqT, const unsigned short* __restrict__ WkT,
    const float* __restrict__ bq, const float* __restrict__ bk,
    const float* __restrict__ w_vol, const float* __restrict__ b_vol,
    const float* __restrict__ w_volu, const float* __restrict__ b_volu,
    float* __restrict__ bp_out, int* __restrict__ flags)
{
    extern __shared__ unsigned short smem[];
    unsigned short* x_lds  = smem;                   // XROWS * LDX
    unsigned short* wq_lds = x_lds + XROWS * LDX;    // 64 * LDX
    unsigned short* wk_lds = wq_lds + 64 * LDX;      // 64 * LDX
    unsigned short* wg_lds = wk_lds + 64 * LDX;      // 16 * LDX

    const int tid = threadIdx.x;
    const int wm  = tid >> 6;
    const int l   = tid & 63;
    const int g   = l >> 4;
    const int c   = l & 15;
    const int b   = blockIdx.y;
    const int s0  = blockIdx.x * MBLK;

    // ---- stage x rows s0-1 .. s0+127 as bf16 (float4 loads, ushort4 writes)
    {
        const float4* x4 = (const float4*)(x + (size_t)b * SN * DN);
        for (int f = tid; f < XROWS * 64; f += 256) {
            int row = f >> 6, c4 = f & 63;
            int gs = s0 - 1 + row;
            float4 v = make_float4(0.f, 0.f, 0.f, 0.f);
            if (gs >= 0) v = x4[(size_t)gs * 64 + c4];
            ushort4 o;
            o.x = f2bf(v.x); o.y = f2bf(v.y); o.z = f2bf(v.z); o.w = f2bf(v.w);
            *(ushort4*)&x_lds[row * LDX + c4 * 4] = o;
        }
        // gate weights tile: row0=w_vol, row1=w_volu, rows 2..15 zero
        for (int e = tid; e < 16 * LDX; e += 256) {
            int row = e / LDX, col = e % LDX;
            float v = 0.f;
            if (col < DN) { if (row == 0) v = w_vol[col]; else if (row == 1) v = w_volu[col]; }
            wg_lds[e] = f2bf(v);
        }
    }

    f32x4 accq[2][4], acck[2][4], accg[2];
    float dt[2][4], nqv[2][4], nkv[2][4];
    #pragma unroll
    for (int m = 0; m < 2; ++m) {
        accg[m] = (f32x4)(0.f);
        #pragma unroll
        for (int r = 0; r < 4; ++r) { dt[m][r] = 0.f; nqv[m][r] = 0.f; nkv[m][r] = 0.f; }
    }

    // per-thread LDS element offsets
    int aoff_q[2], aoff_k[2], boff[4], goff;
    #pragma unroll
    for (int m = 0; m < 2; ++m) {
        int rloc = wm * 32 + m * 16 + c;       // k-window local row (global s-1)
        aoff_k[m] = rloc * LDX + g * 8;
        aoff_q[m] = (rloc + 1) * LDX + g * 8;  // q-window (global s)
    }
    #pragma unroll
    for (int n = 0; n < 4; ++n) boff[n] = (n * 16 + c) * LDX + g * 8;
    goff = c * LDX + g * 8;

    for (int p = 0; p < 4; ++p) {
        const int n0 = p * 64;
        __syncthreads();                        // previous chunk fully consumed
        for (int f = tid; f < 64 * 32; f += 256) {
            int row = f >> 5, c8 = f & 31;
            *(short8*)&wq_lds[row * LDX + c8 * 8] =
                *(const short8*)&WqT[(size_t)(n0 + row) * DN + c8 * 8];
            *(short8*)&wk_lds[row * LDX + c8 * 8] =
                *(const short8*)&WkT[(size_t)(n0 + row) * DN + c8 * 8];
        }
        __syncthreads();

        #pragma unroll
        for (int m = 0; m < 2; ++m)
            #pragma unroll
            for (int n = 0; n < 4; ++n) { accq[m][n] = (f32x4)(0.f); acck[m][n] = (f32x4)(0.f); }

        #pragma unroll 2
        for (int ks = 0; ks < 8; ++ks) {
            const int k0 = ks * 32;
            short8 aq[2], ak[2], bqf[4], bkf[4];
            #pragma unroll
            for (int m = 0; m < 2; ++m) {
                aq[m] = *(const short8*)&x_lds[aoff_q[m] + k0];
                ak[m] = *(const short8*)&x_lds[aoff_k[m] + k0];
            }
            #pragma unroll
            for (int n = 0; n < 4; ++n) {
                bqf[n] = *(const short8*)&wq_lds[boff[n] + k0];
                bkf[n] = *(const short8*)&wk_lds[boff[n] + k0];
            }
            #pragma unroll
            for (int m = 0; m < 2; ++m)
                #pragma unroll
                for (int n = 0; n < 4; ++n) {
                    accq[m][n] = __builtin_amdgcn_mfma_f32_16x16x32_bf16(aq[m], bqf[n], accq[m][n], 0, 0, 0);
                    acck[m][n] = __builtin_amdgcn_mfma_f32_16x16x32_bf16(ak[m], bkf[n], acck[m][n], 0, 0, 0);
                }
            if (p == 0) {
                short8 bg = *(const short8*)&wg_lds[goff + k0];
                #pragma unroll
                for (int m = 0; m < 2; ++m)
                    accg[m] = __builtin_amdgcn_mfma_f32_16x16x32_bf16(aq[m], bg, accg[m], 0, 0, 0);
            }
        }

        // fold this pass's fragments into dot/norm partials (with biases)
        #pragma unroll
        for (int n = 0; n < 4; ++n) {
            float bqv = bq[n0 + n * 16 + c];
            float bkv = bk[n0 + n * 16 + c];
            #pragma unroll
            for (int m = 0; m < 2; ++m)
                #pragma unroll
                for (int r = 0; r < 4; ++r) {
                    float qv = accq[m][n][r] + bqv;
                    float kv = acck[m][n][r] + bkv;
                    dt[m][r]  = fmaf(qv, kv, dt[m][r]);
                    nqv[m][r] = fmaf(qv, qv, nqv[m][r]);
                    nkv[m][r] = fmaf(kv, kv, nkv[m][r]);
                }
        }
    }

    // reduce over the 16 dim-lanes of each group
    #pragma unroll
    for (int m = 0; m < 2; ++m)
        #pragma unroll
        for (int r = 0; r < 4; ++r) {
            float a = dt[m][r], e = nqv[m][r], f = nkv[m][r];
            #pragma unroll
            for (int mask = 1; mask < 16; mask <<= 1) {
                a += __shfl_xor(a, mask);
                e += __shfl_xor(e, mask);
                f += __shfl_xor(f, mask);
            }
            dt[m][r] = a; nqv[m][r] = e; nkv[m][r] = f;
        }
    // gates: lane c==0 holds vl, c==1 holds vu
    float vu_[2][4];
    #pragma unroll
    for (int m = 0; m < 2; ++m)
        #pragma unroll
        for (int r = 0; r < 4; ++r) vu_[m][r] = __shfl_xor(accg[m][r], 1);

    if (c == 0) {
        const float bv = b_vol[0], bu = b_volu[0];
        #pragma unroll
        for (int m = 0; m < 2; ++m)
            #pragma unroll
            for (int r = 0; r < 4; ++r) {
                int s = s0 + wm * 32 + m * 16 + g * 4 + r;
                float comb;
                if (s == 0) comb = 1.0f;
                else {
                    float denom = fmaxf(sqrtf(nqv[m][r]), EPSF) * fmaxf(sqrtf(nkv[m][r]), EPSF);
                    float sim   = dt[m][r] / denom;
                    float vol   = 1.f / (1.f + expf(-(accg[m][r] + bv)));
                    float volu  = 1.f / (1.f + expf(-(vu_[m][r] + bu)));
                    comb = (1.f - sim) + 0.3f * vol + 0.2f * volu;
                }
                float pbp = 1.f / (1.f + expf(-comb));
                size_t o = (size_t)b * SN + s;
                bp_out[o] = pbp;
                flags[o]  = (pbp > 0.5f) ? 1 : 0;
            }
    }
}

// ---------------------------------------------------------------------------
// k2: per-batch scan of hard flags -> packed dest index, count, boundary sum
// ---------------------------------------------------------------------------
__global__ void k2_scan(const int* __restrict__ flags,
                        const float* __restrict__ bp,
                        int* __restrict__ pidx,
                        int* __restrict__ cnt,
                        float* __restrict__ bsum)
{
    const int b = blockIdx.x;
    const int t = threadIdx.x;
    __shared__ int   ssum[256];
    __shared__ float sf[256];

    const size_t base = (size_t)b * SN + (size_t)t * 32;
    int f[32];
    int run = 0;
    float fs = 0.f;
    #pragma unroll
    for (int i = 0; i < 32; ++i) {
        f[i] = flags[base + i];
        run += f[i];
        float p  = bp[base + i];
        float hf = (float)f[i];
        fs += hf + p - p;
    }
    ssum[t] = run;
    sf[t]   = fs;
    __syncthreads();

    for (int off = 1; off < 256; off <<= 1) {
        int v = (t >= off) ? ssum[t - off] : 0;
        __syncthreads();
        ssum[t] += v;
        __syncthreads();
    }
    const int incl = ssum[t];
    int running = incl - run;
    #pragma unroll
    for (int i = 0; i < 32; ++i) {
        running += f[i];
        pidx[base + i] = f[i] ? (running - 1) : -1;
    }
    if (t == 255) cnt[b] = incl;

    for (int off = 128; off > 0; off >>= 1) {
        if (t < off) sf[t] += sf[t + off];
        __syncthreads();
    }
    if (t == 0) bsum[b] = sf[0];
}

// ---------------------------------------------------------------------------
// k3: gather-copy hard rows; 4 rows per 256-thread block
// ---------------------------------------------------------------------------
__global__ void k3_scatter(const float* __restrict__ x,
                           const int* __restrict__ pidx,
                           float* __restrict__ out_comp)
{
    const int row  = blockIdx.x * 4 + (threadIdx.x >> 6);   // b*SN + s
    const int lane = threadIdx.x & 63;
    const int p = pidx[row];
    if (p < 0) return;
    const int b = row >> 13;                                 // SN = 8192
    const float4* src = (const float4*)(x + (size_t)row * DN);
    float4* dst = (float4*)(out_comp + ((size_t)b * SN + p) * DN);
    dst[lane] = src[lane];
}

// k3b: zero destination rows beyond each batch's boundary count
__global__ void k3b_zerotail(float* __restrict__ out_comp,
                             const int* __restrict__ cnt)
{
    const int gid = blockIdx.x * blockDim.x + threadIdx.x;
    const int b = gid >> 13;
    const int j = gid & (SN - 1);
    if (j >= cnt[b]) {
        float4* dst = (float4*)(out_comp + ((size_t)b * SN + j) * DN);
        const float4 z = make_float4(0.f, 0.f, 0.f, 0.f);
        for (int i = 0; i < DN / 4; ++i) dst[i] = z;
    }
}

// k4: ratio loss
__global__ void k4_loss(const float* __restrict__ bsum, float* __restrict__ out_rl)
{
    if (threadIdx.x == 0) {
        float acc = 0.f;
        for (int i = 0; i < BN; ++i) acc += bsum[i];
        float mean = acc / (float)BN;
        float d = mean - (float)(SN / 4);
        out_rl[0] = d * d;
    }
}

extern "C" void kernel_launch(void* const* d_in, const int* in_sizes, int n_in,
                              void* d_out, int out_size, void* d_ws, size_t ws_size,
                              hipStream_t stream) {
    const float* x      = (const float*)d_in[0];
    const float* Wq     = (const float*)d_in[1];
    const float* bq     = (const float*)d_in[2];
    const float* Wk     = (const float*)d_in[3];
    const float* bk     = (const float*)d_in[4];
    const float* w_vol  = (const float*)d_in[5];
    const float* b_vol  = (const float*)d_in[6];
    const float* w_volu = (const float*)d_in[7];
    const float* b_volu = (const float*)d_in[8];

    float* out_comp = (float*)d_out;                       // B*S*D
    float* out_bp   = out_comp + (size_t)BN * SN * DN;     // B*S
    float* out_rl   = out_bp + (size_t)BN * SN;            // 1

    int*   flags = (int*)d_ws;                             // B*S
    int*   pidx  = flags + (size_t)BN * SN;                // B*S
    int*   cnt   = pidx + (size_t)BN * SN;                 // B
    float* bsum  = (float*)(cnt + BN);                     // B
    unsigned short* WqT = (unsigned short*)(bsum + BN);    // D*D bf16
    unsigned short* WkT = WqT + (size_t)DN * DN;           // D*D bf16

    k0_prep<<<DN, DN, 0, stream>>>(Wq, Wk, WqT, WkT);

    const int lds_bytes = (XROWS + 64 + 64 + 16) * LDX * 2;   // 144,144 B
    static bool attr_set_done = false;
    hipFuncSetAttribute((const void*)k1_mfma,
                        hipFuncAttributeMaxDynamicSharedMemorySize, lds_bytes);
    (void)attr_set_done;

    k1_mfma<<<dim3(SN / MBLK, BN), 256, lds_bytes, stream>>>(
        x, WqT, WkT, bq, bk, w_vol, b_vol, w_volu, b_volu, out_bp, flags);

    k2_scan<<<BN, 256, 0, stream>>>(flags, out_bp, pidx, cnt, bsum);

    k3_scatter<<<(BN * SN) / 4, 256, 0, stream>>>(x, pidx, out_comp);

    k3b_zerotail<<<(BN * SN) / 256, 256, 0, stream>>>(out_comp, cnt);

    k4_loss<<<1, 64, 0, stream>>>(bsum, out_rl);
}

// Round 3
// 205.768 us; speedup vs baseline: 3.2249x; 1.0208x over previous
//
#include <hip/hip_runtime.h>
#include <math.h>

#define BN 16
#define SN 8192
#define DN 256
#define MBLK 128
#define XROWS 129            // MBLK + 1 halo row
#define EPSF 1e-8f

typedef __attribute__((ext_vector_type(8))) short short8;
typedef __attribute__((ext_vector_type(4))) float f32x4;

__device__ __forceinline__ unsigned short f2bf(float f) {
    union { float f; unsigned int u; } cv; cv.f = f;
    unsigned int u = cv.u + 0x7FFFu + ((cv.u >> 16) & 1u);
    return (unsigned short)(u >> 16);
}

// ---------------------------------------------------------------------------
// k0: transpose+convert weights to bf16 WT[n][k]; build 16x256 gate B-tile
//     (row0 = w_vol, row1 = w_volu, rows 2..15 = 0).
// ---------------------------------------------------------------------------
__global__ void k0_prep(const float* __restrict__ Wq, const float* __restrict__ Wk,
                        const float* __restrict__ w_vol, const float* __restrict__ w_volu,
                        unsigned short* __restrict__ WqT, unsigned short* __restrict__ WkT,
                        unsigned short* __restrict__ gateB)
{
    const int n = blockIdx.x;
    const int k = threadIdx.x;
    WqT[(size_t)n * DN + k] = f2bf(Wq[(size_t)k * DN + n]);
    WkT[(size_t)n * DN + k] = f2bf(Wk[(size_t)k * DN + n]);
    if (n < 16) {
        float v = (n == 0) ? w_vol[k] : ((n == 1) ? w_volu[k] : 0.0f);
        gateB[(size_t)n * DN + k] = f2bf(v);
    }
}

// ---------------------------------------------------------------------------
// k1: MFMA q/k projection + neighbor similarity + gates.
// 256 threads (4 waves), 128 seq rows/block. x tile (129 rows, halo) bf16 in
// LDS, XOR-swizzled, read ONCE into A-register fragments. B-fragments stream
// straight from L2 (WqT/WkT/gateB). No barriers in the main loop.
// ---------------------------------------------------------------------------
__global__ __launch_bounds__(256, 2) void k1_mfma(
    const float* __restrict__ x,
    const unsigned short* __restrict__ WqT,
    const unsigned short* __restrict__ WkT,
    const unsigned short* __restrict__ gateB,
    const float* __restrict__ bq, const float* __restrict__ bk,
    const float* __restrict__ b_vol, const float* __restrict__ b_volu,
    float* __restrict__ bp_out, int* __restrict__ flags)
{
    extern __shared__ unsigned char smem_raw[];      // XROWS*512 bytes
    unsigned short* xs = (unsigned short*)smem_raw;

    const int tid = threadIdx.x;
    const int wm  = tid >> 6;
    const int l   = tid & 63;
    const int g   = l >> 4;
    const int c   = l & 15;
    const int b   = blockIdx.y;
    const int s0  = blockIdx.x * MBLK;

    // ---- stage x rows s0-1 .. s0+127 as bf16, 16B chunks, XOR-swizzled
    {
        const float* xb = x + (size_t)b * SN * DN;
        for (int f = tid; f < XROWS * 32; f += 256) {
            const int row = f >> 5, ch = f & 31;
            const int gs = s0 - 1 + row;
            float v[8];
            if (gs >= 0) {
                const float4* p = (const float4*)(xb + (size_t)gs * DN + ch * 8);
                float4 a = p[0], d = p[1];
                v[0] = a.x; v[1] = a.y; v[2] = a.z; v[3] = a.w;
                v[4] = d.x; v[5] = d.y; v[6] = d.z; v[7] = d.w;
            } else {
                #pragma unroll
                for (int i = 0; i < 8; ++i) v[i] = 0.0f;
            }
            short8 sv;
            #pragma unroll
            for (int i = 0; i < 8; ++i) sv[i] = (short)f2bf(v[i]);
            const int byte = row * 512 + ((ch * 16) ^ ((row & 7) << 4));
            *(short8*)((char*)xs + byte) = sv;
        }
    }
    __syncthreads();

    // ---- A fragments -> registers (q window = k window shifted by one row)
    short8 aq[2][8], ak[2][8];
    #pragma unroll
    for (int m = 0; m < 2; ++m) {
        const int rk = wm * 32 + m * 16 + c;     // LDS row (= seq s0-1+rk)
        const int rq = rk + 1;
        #pragma unroll
        for (int ks = 0; ks < 8; ++ks) {
            const int oq = rq * 512 + (((ks * 64) + g * 16) ^ ((rq & 7) << 4));
            const int ok = rk * 512 + (((ks * 64) + g * 16) ^ ((rk & 7) << 4));
            aq[m][ks] = *(const short8*)((const char*)xs + oq);
            ak[m][ks] = *(const short8*)((const char*)xs + ok);
        }
    }

    float dt[2][4], nqv[2][4], nkv[2][4];
    #pragma unroll
    for (int m = 0; m < 2; ++m)
        #pragma unroll
        for (int r = 0; r < 4; ++r) { dt[m][r] = 0.f; nqv[m][r] = 0.f; nkv[m][r] = 0.f; }

    // ---- main loop: n-chunks of 16 output cols; B streamed from L2
    #pragma unroll 2
    for (int n = 0; n < 16; ++n) {
        const short8* bq8 = (const short8*)(WqT + ((size_t)(n * 16 + c)) * DN + g * 8);
        const short8* bk8 = (const short8*)(WkT + ((size_t)(n * 16 + c)) * DN + g * 8);
        f32x4 cq[2], ck[2];
        cq[0] = (f32x4)(0.f); cq[1] = (f32x4)(0.f);
        ck[0] = (f32x4)(0.f); ck[1] = (f32x4)(0.f);
        #pragma unroll
        for (int ks = 0; ks < 8; ++ks) {
            const short8 bqf = bq8[ks * 4];      // ks*32 elems = ks*4 short8
            const short8 bkf = bk8[ks * 4];
            cq[0] = __builtin_amdgcn_mfma_f32_16x16x32_bf16(aq[0][ks], bqf, cq[0], 0, 0, 0);
            cq[1] = __builtin_amdgcn_mfma_f32_16x16x32_bf16(aq[1][ks], bqf, cq[1], 0, 0, 0);
            ck[0] = __builtin_amdgcn_mfma_f32_16x16x32_bf16(ak[0][ks], bkf, ck[0], 0, 0, 0);
            ck[1] = __builtin_amdgcn_mfma_f32_16x16x32_bf16(ak[1][ks], bkf, ck[1], 0, 0, 0);
        }
        const float bqv = bq[n * 16 + c];
        const float bkv = bk[n * 16 + c];
        #pragma unroll
        for (int m = 0; m < 2; ++m)
            #pragma unroll
            for (int r = 0; r < 4; ++r) {
                const float qv = cq[m][r] + bqv;
                const float kv = ck[m][r] + bkv;
                dt[m][r]  = fmaf(qv, kv, dt[m][r]);
                nqv[m][r] = fmaf(qv, qv, nqv[m][r]);
                nkv[m][r] = fmaf(kv, kv, nkv[m][r]);
            }
    }

    // ---- gates (cols 0/1 of a 16-wide tile)
    f32x4 cg[2];
    cg[0] = (f32x4)(0.f); cg[1] = (f32x4)(0.f);
    {
        const short8* bg8 = (const short8*)(gateB + (size_t)c * DN + g * 8);
        #pragma unroll
        for (int ks = 0; ks < 8; ++ks) {
            const short8 bgf = bg8[ks * 4];
            cg[0] = __builtin_amdgcn_mfma_f32_16x16x32_bf16(aq[0][ks], bgf, cg[0], 0, 0, 0);
            cg[1] = __builtin_amdgcn_mfma_f32_16x16x32_bf16(aq[1][ks], bgf, cg[1], 0, 0, 0);
        }
    }

    // ---- reduce over the 16 dim-lanes of each group
    #pragma unroll
    for (int m = 0; m < 2; ++m)
        #pragma unroll
        for (int r = 0; r < 4; ++r) {
            float a = dt[m][r], e = nqv[m][r], f = nkv[m][r];
            #pragma unroll
            for (int mask = 1; mask < 16; mask <<= 1) {
                a += __shfl_xor(a, mask);
                e += __shfl_xor(e, mask);
                f += __shfl_xor(f, mask);
            }
            dt[m][r] = a; nqv[m][r] = e; nkv[m][r] = f;
        }
    float vu_[2][4];
    #pragma unroll
    for (int m = 0; m < 2; ++m)
        #pragma unroll
        for (int r = 0; r < 4; ++r) vu_[m][r] = __shfl_xor(cg[m][r], 1);

    if (c == 0) {
        const float bv = b_vol[0], bu = b_volu[0];
        #pragma unroll
        for (int m = 0; m < 2; ++m)
            #pragma unroll
            for (int r = 0; r < 4; ++r) {
                const int s = s0 + wm * 32 + m * 16 + g * 4 + r;
                float comb;
                if (s == 0) comb = 1.0f;
                else {
                    float denom = fmaxf(sqrtf(nqv[m][r]), EPSF) * fmaxf(sqrtf(nkv[m][r]), EPSF);
                    float sim   = dt[m][r] / denom;
                    float vol   = 1.f / (1.f + expf(-(cg[m][r] + bv)));
                    float volu  = 1.f / (1.f + expf(-(vu_[m][r] + bu)));
                    comb = (1.f - sim) + 0.3f * vol + 0.2f * volu;
                }
                const float pbp = 1.f / (1.f + expf(-comb));
                const size_t o = (size_t)b * SN + s;
                bp_out[o] = pbp;
                flags[o]  = (pbp > 0.5f) ? 1 : 0;
            }
    }
}

// ---------------------------------------------------------------------------
// k2: per-batch scan of hard flags -> packed dest index, count, boundary sum
// ---------------------------------------------------------------------------
__global__ void k2_scan(const int* __restrict__ flags,
                        const float* __restrict__ bp,
                        int* __restrict__ pidx,
                        int* __restrict__ cnt,
                        float* __restrict__ bsum)
{
    const int b = blockIdx.x;
    const int t = threadIdx.x;
    __shared__ int   ssum[256];
    __shared__ float sf[256];

    const size_t base = (size_t)b * SN + (size_t)t * 32;
    int f[32];
    int run = 0;
    float fs = 0.f;
    #pragma unroll
    for (int i = 0; i < 32; ++i) {
        f[i] = flags[base + i];
        run += f[i];
        float p  = bp[base + i];
        float hf = (float)f[i];
        fs += hf + p - p;
    }
    ssum[t] = run;
    sf[t]   = fs;
    __syncthreads();

    for (int off = 1; off < 256; off <<= 1) {
        int v = (t >= off) ? ssum[t - off] : 0;
        __syncthreads();
        ssum[t] += v;
        __syncthreads();
    }
    const int incl = ssum[t];
    int running = incl - run;
    #pragma unroll
    for (int i = 0; i < 32; ++i) {
        running += f[i];
        pidx[base + i] = f[i] ? (running - 1) : -1;
    }
    if (t == 255) cnt[b] = incl;

    for (int off = 128; off > 0; off >>= 1) {
        if (t < off) sf[t] += sf[t + off];
        __syncthreads();
    }
    if (t == 0) bsum[b] = sf[0];
}

// ---------------------------------------------------------------------------
// k3: gather-copy hard rows; 4 rows per 256-thread block
// ---------------------------------------------------------------------------
__global__ void k3_scatter(const float* __restrict__ x,
                           const int* __restrict__ pidx,
                           float* __restrict__ out_comp)
{
    const int row  = blockIdx.x * 4 + (threadIdx.x >> 6);
    const int lane = threadIdx.x & 63;
    const int p = pidx[row];
    if (p < 0) return;
    const int b = row >> 13;
    const float4* src = (const float4*)(x + (size_t)row * DN);
    float4* dst = (float4*)(out_comp + ((size_t)b * SN + p) * DN);
    dst[lane] = src[lane];
}

// k3b: zero destination rows beyond each batch's boundary count
__global__ void k3b_zerotail(float* __restrict__ out_comp,
                             const int* __restrict__ cnt)
{
    const int gid = blockIdx.x * blockDim.x + threadIdx.x;
    const int b = gid >> 13;
    const int j = gid & (SN - 1);
    if (j >= cnt[b]) {
        float4* dst = (float4*)(out_comp + ((size_t)b * SN + j) * DN);
        const float4 z = make_float4(0.f, 0.f, 0.f, 0.f);
        for (int i = 0; i < DN / 4; ++i) dst[i] = z;
    }
}

// k4: ratio loss
__global__ void k4_loss(const float* __restrict__ bsum, float* __restrict__ out_rl)
{
    if (threadIdx.x == 0) {
        float acc = 0.f;
        for (int i = 0; i < BN; ++i) acc += bsum[i];
        float mean = acc / (float)BN;
        float d = mean - (float)(SN / 4);
        out_rl[0] = d * d;
    }
}

extern "C" void kernel_launch(void* const* d_in, const int* in_sizes, int n_in,
                              void* d_out, int out_size, void* d_ws, size_t ws_size,
                              hipStream_t stream) {
    const float* x      = (const float*)d_in[0];
    const float* Wq     = (const float*)d_in[1];
    const float* bq     = (const float*)d_in[2];
    const float* Wk     = (const float*)d_in[3];
    const float* bk     = (const float*)d_in[4];
    const float* w_vol  = (const float*)d_in[5];
    const float* b_vol  = (const float*)d_in[6];
    const float* w_volu = (const float*)d_in[7];
    const float* b_volu = (const float*)d_in[8];

    float* out_comp = (float*)d_out;                       // B*S*D
    float* out_bp   = out_comp + (size_t)BN * SN * DN;     // B*S
    float* out_rl   = out_bp + (size_t)BN * SN;            // 1

    int*   flags = (int*)d_ws;                             // B*S
    int*   pidx  = flags + (size_t)BN * SN;                // B*S
    int*   cnt   = pidx + (size_t)BN * SN;                 // B
    float* bsum  = (float*)(cnt + BN);                     // B
    unsigned short* WqT   = (unsigned short*)(bsum + BN);  // D*D bf16
    unsigned short* WkT   = WqT + (size_t)DN * DN;         // D*D bf16
    unsigned short* gateB = WkT + (size_t)DN * DN;         // 16*D bf16

    k0_prep<<<DN, DN, 0, stream>>>(Wq, Wk, w_vol, w_volu, WqT, WkT, gateB);

    const int lds_bytes = XROWS * 512;                     // 66,048 B
    hipFuncSetAttribute((const void*)k1_mfma,
                        hipFuncAttributeMaxDynamicSharedMemorySize, lds_bytes);

    k1_mfma<<<dim3(SN / MBLK, BN), 256, lds_bytes, stream>>>(
        x, WqT, WkT, gateB, bq, bk, b_vol, b_volu, out_bp, flags);

    k2_scan<<<BN, 256, 0, stream>>>(flags, out_bp, pidx, cnt, bsum);

    k3_scatter<<<(BN * SN) / 4, 256, 0, stream>>>(x, pidx, out_comp);

    k3b_zerotail<<<(BN * SN) / 256, 256, 0, stream>>>(out_comp, cnt);

    k4_loss<<<1, 64, 0, stream>>>(bsum, out_rl);
}

// Round 4
// 174.402 us; speedup vs baseline: 3.8049x; 1.1798x over previous
//
#include <hip/hip_runtime.h>
#include <math.h>

#define BN 16
#define SN 8192
#define DN 256
#define MBLK 128
#define EPSF 1e-8f

typedef __attribute__((ext_vector_type(8))) short short8;
typedef __attribute__((ext_vector_type(4))) float f32x4;

typedef const __attribute__((address_space(1))) unsigned int g_u32;
typedef __attribute__((address_space(3))) unsigned int l_u32;

__device__ __forceinline__ unsigned short f2bf(float f) {
    union { float f; unsigned int u; } cv; cv.f = f;
    unsigned int u = cv.u + 0x7FFFu + ((cv.u >> 16) & 1u);
    return (unsigned short)(u >> 16);
}

__device__ __forceinline__ short8 pack8(float4 lo, float4 hi) {
    short8 r;
    r[0] = (short)f2bf(lo.x); r[1] = (short)f2bf(lo.y);
    r[2] = (short)f2bf(lo.z); r[3] = (short)f2bf(lo.w);
    r[4] = (short)f2bf(hi.x); r[5] = (short)f2bf(hi.y);
    r[6] = (short)f2bf(hi.z); r[7] = (short)f2bf(hi.w);
    return r;
}

__device__ __forceinline__ void gload_lds16(const void* g, void* l) {
    __builtin_amdgcn_global_load_lds((g_u32*)g, (l_u32*)l, 16, 0, 0);
}

// ---------------------------------------------------------------------------
// k0: rewrite Wq/Wk into frag-major bf16 layout (8 chunks x 32KB) + gate tile.
// Element (n_col, k): chunk=n>>5, f=(n>>4)&1, cc=n&15, ks=(k/8)>>2, g=(k/8)&3,
// e=k&7.  byte = chunk*32768 + ((mat*2+f)*8+ks)*1024 + (g*16+cc)*16 + e*2.
// A ds_read_b128 of one fragment is then base + lane*16 : conflict-free.
// ---------------------------------------------------------------------------
__global__ void k0_prep(const float* __restrict__ Wq, const float* __restrict__ Wk,
                        const float* __restrict__ w_vol, const float* __restrict__ w_volu,
                        unsigned char* __restrict__ Wfrag, unsigned char* __restrict__ Gfrag)
{
    const int tid = threadIdx.x;
    const int n   = blockIdx.x * 8 + (tid >> 5);   // 0..255
    const int k8  = tid & 31;                      // 8-elem group of K
    const int ch  = n >> 5;
    const int f   = (n >> 4) & 1;
    const int cc  = n & 15;
    const int ks  = k8 >> 2;
    const int g   = k8 & 3;

    short8 vq, vk;
    #pragma unroll
    for (int e = 0; e < 8; ++e) {
        const int k = k8 * 8 + e;
        vq[e] = (short)f2bf(Wq[(size_t)k * DN + n]);
        vk[e] = (short)f2bf(Wk[(size_t)k * DN + n]);
    }
    const size_t base = (size_t)ch * 32768 + (size_t)((g * 16 + cc) * 16);
    *(short8*)(Wfrag + base + ((0 * 2 + f) * 8 + ks) * 1024) = vq;
    *(short8*)(Wfrag + base + ((1 * 2 + f) * 8 + ks) * 1024) = vk;

    // gate tile: 8KB, frag ks: lane (g,cc): col cc: 0=w_vol, 1=w_volu, else 0
    if (blockIdx.x < 2) {
        const int gc = blockIdx.x * 8 + (tid >> 5);   // cc 0..15
        short8 vg;
        #pragma unroll
        for (int e = 0; e < 8; ++e) {
            const int k = k8 * 8 + e;
            float v = (gc == 0) ? w_vol[k] : ((gc == 1) ? w_volu[k] : 0.0f);
            vg[e] = (short)f2bf(v);
        }
        *(short8*)(Gfrag + (size_t)ks * 1024 + (size_t)((g * 16 + gc) * 16)) = vg;
    }
}

// ---------------------------------------------------------------------------
// k1: MFMA q/k projection + neighbor similarity + gates.
// 256 threads (4 waves), 128 seq rows/block. A-fragments gathered from global
// x (fp32->bf16, registers, no LDS). W streamed chunk-by-chunk into LDS via
// global_load_lds (double-buffered 2x32KB), ds_read_b128 conflict-free.
// ---------------------------------------------------------------------------
__global__ __launch_bounds__(256, 2) void k1_mfma(
    const float* __restrict__ x,
    const unsigned char* __restrict__ Wfrag,
    const unsigned char* __restrict__ Gfrag,
    const float* __restrict__ bq, const float* __restrict__ bk,
    const float* __restrict__ b_vol, const float* __restrict__ b_volu,
    float* __restrict__ bp_out, int* __restrict__ flags)
{
    extern __shared__ unsigned char lds[];           // 73728 B
    unsigned char* bufs  = lds;                      // 2 x 32768
    unsigned char* lgate = lds + 65536;              // 8192

    const int tid = threadIdx.x;
    const int wm  = tid >> 6;
    const int l   = tid & 63;
    const int g   = l >> 4;
    const int c   = l & 15;
    const int b   = blockIdx.y;
    const int s0  = blockIdx.x * MBLK;
    const int wv  = tid >> 6;

    // ---- issue stage of chunk 0 + gate tile (async, vmcnt-counted)
    #pragma unroll
    for (int j = 0; j < 8; ++j)
        gload_lds16(Wfrag + j * 4096 + tid * 16, bufs + j * 4096 + wv * 1024);
    #pragma unroll
    for (int j = 0; j < 2; ++j)
        gload_lds16(Gfrag + j * 4096 + tid * 16, lgate + j * 4096 + wv * 1024);

    // ---- A-gather: q/k windows straight from global fp32 -> bf16 registers
    const float* xw = x + (size_t)b * SN * DN;
    short8 aq[2][8], ak[2][8];
    #pragma unroll
    for (int m = 0; m < 2; ++m) {
        const int rq = s0 + wm * 32 + m * 16 + c;     // q row (seq s)
        const int rk = rq - 1;                        // k row (seq s-1)
        {
            float4 t[16];
            const float* pr = xw + (size_t)rq * DN + g * 8;
            #pragma unroll
            for (int ks = 0; ks < 8; ++ks) {
                t[ks * 2]     = ((const float4*)(pr + ks * 32))[0];
                t[ks * 2 + 1] = ((const float4*)(pr + ks * 32))[1];
            }
            #pragma unroll
            for (int ks = 0; ks < 8; ++ks)
                aq[m][ks] = pack8(t[ks * 2], t[ks * 2 + 1]);
        }
        {
            float4 t[16];
            const bool ok = (rk >= 0);
            const float* pr = xw + (size_t)(ok ? rk : 0) * DN + g * 8;
            const float4 z = make_float4(0.f, 0.f, 0.f, 0.f);
            #pragma unroll
            for (int ks = 0; ks < 8; ++ks) {
                t[ks * 2]     = ok ? ((const float4*)(pr + ks * 32))[0] : z;
                t[ks * 2 + 1] = ok ? ((const float4*)(pr + ks * 32))[1] : z;
            }
            #pragma unroll
            for (int ks = 0; ks < 8; ++ks)
                ak[m][ks] = pack8(t[ks * 2], t[ks * 2 + 1]);
        }
    }

    float dt[2][4], nqv[2][4], nkv[2][4];
    #pragma unroll
    for (int m = 0; m < 2; ++m)
        #pragma unroll
        for (int r = 0; r < 4; ++r) { dt[m][r] = 0.f; nqv[m][r] = 0.f; nkv[m][r] = 0.f; }

    // chunk 0 + gate must be resident before first read
    asm volatile("s_waitcnt vmcnt(0)" ::: "memory");
    __builtin_amdgcn_s_barrier();

    // ---- main loop: 8 chunks of 32 output cols (q and k both in each chunk)
    #pragma unroll
    for (int i = 0; i < 8; ++i) {
        // issue stage of next chunk into the other buffer
        if (i < 7) {
            const unsigned char* src = Wfrag + (size_t)(i + 1) * 32768;
            unsigned char* dst = bufs + ((i + 1) & 1) * 32768;
            #pragma unroll
            for (int j = 0; j < 8; ++j)
                gload_lds16(src + j * 4096 + tid * 16, dst + j * 4096 + wv * 1024);
        }

        const unsigned char* bb = bufs + (i & 1) * 32768;
        f32x4 cq[2][2], ck[2][2];
        #pragma unroll
        for (int m = 0; m < 2; ++m)
            #pragma unroll
            for (int nf = 0; nf < 2; ++nf) { cq[m][nf] = (f32x4)(0.f); ck[m][nf] = (f32x4)(0.f); }

        #pragma unroll
        for (int ks = 0; ks < 8; ++ks) {
            #pragma unroll
            for (int nf = 0; nf < 2; ++nf) {
                const short8 bqf = *(const short8*)(bb + ((0 * 2 + nf) * 8 + ks) * 1024 + l * 16);
                const short8 bkf = *(const short8*)(bb + ((1 * 2 + nf) * 8 + ks) * 1024 + l * 16);
                cq[0][nf] = __builtin_amdgcn_mfma_f32_16x16x32_bf16(aq[0][ks], bqf, cq[0][nf], 0, 0, 0);
                cq[1][nf] = __builtin_amdgcn_mfma_f32_16x16x32_bf16(aq[1][ks], bqf, cq[1][nf], 0, 0, 0);
                ck[0][nf] = __builtin_amdgcn_mfma_f32_16x16x32_bf16(ak[0][ks], bkf, ck[0][nf], 0, 0, 0);
                ck[1][nf] = __builtin_amdgcn_mfma_f32_16x16x32_bf16(ak[1][ks], bkf, ck[1][nf], 0, 0, 0);
            }
        }

        // fold chunk's q/k values into dot/norm partials (with biases)
        #pragma unroll
        for (int nf = 0; nf < 2; ++nf) {
            const float bqv = bq[i * 32 + nf * 16 + c];
            const float bkv = bk[i * 32 + nf * 16 + c];
            #pragma unroll
            for (int m = 0; m < 2; ++m)
                #pragma unroll
                for (int r = 0; r < 4; ++r) {
                    const float qv = cq[m][nf][r] + bqv;
                    const float kv = ck[m][nf][r] + bkv;
                    dt[m][r]  = fmaf(qv, kv, dt[m][r]);
                    nqv[m][r] = fmaf(qv, qv, nqv[m][r]);
                    nkv[m][r] = fmaf(kv, kv, nkv[m][r]);
                }
        }

        // next chunk staged + all waves done reading this buffer
        asm volatile("s_waitcnt vmcnt(0)" ::: "memory");
        __builtin_amdgcn_s_barrier();
    }

    // ---- gates (16-col tile, col0=vol, col1=volu), gate LDS never overwritten
    f32x4 cg[2];
    cg[0] = (f32x4)(0.f); cg[1] = (f32x4)(0.f);
    #pragma unroll
    for (int ks = 0; ks < 8; ++ks) {
        const short8 bgf = *(const short8*)(lgate + ks * 1024 + l * 16);
        cg[0] = __builtin_amdgcn_mfma_f32_16x16x32_bf16(aq[0][ks], bgf, cg[0], 0, 0, 0);
        cg[1] = __builtin_amdgcn_mfma_f32_16x16x32_bf16(aq[1][ks], bgf, cg[1], 0, 0, 0);
    }

    // ---- reduce over the 16 dim-lanes of each group
    #pragma unroll
    for (int m = 0; m < 2; ++m)
        #pragma unroll
        for (int r = 0; r < 4; ++r) {
            float a = dt[m][r], e = nqv[m][r], f = nkv[m][r];
            #pragma unroll
            for (int mask = 1; mask < 16; mask <<= 1) {
                a += __shfl_xor(a, mask);
                e += __shfl_xor(e, mask);
                f += __shfl_xor(f, mask);
            }
            dt[m][r] = a; nqv[m][r] = e; nkv[m][r] = f;
        }
    float vu_[2][4];
    #pragma unroll
    for (int m = 0; m < 2; ++m)
        #pragma unroll
        for (int r = 0; r < 4; ++r) vu_[m][r] = __shfl_xor(cg[m][r], 1);

    if (c == 0) {
        const float bv = b_vol[0], bu = b_volu[0];
        #pragma unroll
        for (int m = 0; m < 2; ++m)
            #pragma unroll
            for (int r = 0; r < 4; ++r) {
                const int s = s0 + wm * 32 + m * 16 + g * 4 + r;
                float comb;
                if (s == 0) comb = 1.0f;
                else {
                    float denom = fmaxf(sqrtf(nqv[m][r]), EPSF) * fmaxf(sqrtf(nkv[m][r]), EPSF);
                    float sim   = dt[m][r] / denom;
                    float vol   = 1.f / (1.f + expf(-(cg[m][r] + bv)));
                    float volu  = 1.f / (1.f + expf(-(vu_[m][r] + bu)));
                    comb = (1.f - sim) + 0.3f * vol + 0.2f * volu;
                }
                const float pbp = 1.f / (1.f + expf(-comb));
                const size_t o = (size_t)b * SN + s;
                bp_out[o] = pbp;
                flags[o]  = (pbp > 0.5f) ? 1 : 0;
            }
    }
}

// ---------------------------------------------------------------------------
// k2: per-batch scan of hard flags -> packed dest index, count, boundary sum
// ---------------------------------------------------------------------------
__global__ void k2_scan(const int* __restrict__ flags,
                        const float* __restrict__ bp,
                        int* __restrict__ pidx,
                        int* __restrict__ cnt,
                        float* __restrict__ bsum)
{
    const int b = blockIdx.x;
    const int t = threadIdx.x;
    __shared__ int   ssum[256];
    __shared__ float sf[256];

    const size_t base = (size_t)b * SN + (size_t)t * 32;
    int f[32];
    int run = 0;
    float fs = 0.f;
    #pragma unroll
    for (int i = 0; i < 32; ++i) {
        f[i] = flags[base + i];
        run += f[i];
        float p  = bp[base + i];
        float hf = (float)f[i];
        fs += hf + p - p;
    }
    ssum[t] = run;
    sf[t]   = fs;
    __syncthreads();

    for (int off = 1; off < 256; off <<= 1) {
        int v = (t >= off) ? ssum[t - off] : 0;
        __syncthreads();
        ssum[t] += v;
        __syncthreads();
    }
    const int incl = ssum[t];
    int running = incl - run;
    #pragma unroll
    for (int i = 0; i < 32; ++i) {
        running += f[i];
        pidx[base + i] = f[i] ? (running - 1) : -1;
    }
    if (t == 255) cnt[b] = incl;

    for (int off = 128; off > 0; off >>= 1) {
        if (t < off) sf[t] += sf[t + off];
        __syncthreads();
    }
    if (t == 0) bsum[b] = sf[0];
}

// ---------------------------------------------------------------------------
// k3: gather-copy hard rows; 4 rows per 256-thread block
// ---------------------------------------------------------------------------
__global__ void k3_scatter(const float* __restrict__ x,
                           const int* __restrict__ pidx,
                           float* __restrict__ out_comp)
{
    const int row  = blockIdx.x * 4 + (threadIdx.x >> 6);
    const int lane = threadIdx.x & 63;
    const int p = pidx[row];
    if (p < 0) return;
    const int b = row >> 13;
    const float4* src = (const float4*)(x + (size_t)row * DN);
    float4* dst = (float4*)(out_comp + ((size_t)b * SN + p) * DN);
    dst[lane] = src[lane];
}

// k3b: zero destination rows beyond each batch's boundary count
__global__ void k3b_zerotail(float* __restrict__ out_comp,
                             const int* __restrict__ cnt)
{
    const int gid = blockIdx.x * blockDim.x + threadIdx.x;
    const int b = gid >> 13;
    const int j = gid & (SN - 1);
    if (j >= cnt[b]) {
        float4* dst = (float4*)(out_comp + ((size_t)b * SN + j) * DN);
        const float4 z = make_float4(0.f, 0.f, 0.f, 0.f);
        for (int i = 0; i < DN / 4; ++i) dst[i] = z;
    }
}

// k4: ratio loss
__global__ void k4_loss(const float* __restrict__ bsum, float* __restrict__ out_rl)
{
    if (threadIdx.x == 0) {
        float acc = 0.f;
        for (int i = 0; i < BN; ++i) acc += bsum[i];
        float mean = acc / (float)BN;
        float d = mean - (float)(SN / 4);
        out_rl[0] = d * d;
    }
}

extern "C" void kernel_launch(void* const* d_in, const int* in_sizes, int n_in,
                              void* d_out, int out_size, void* d_ws, size_t ws_size,
                              hipStream_t stream) {
    const float* x      = (const float*)d_in[0];
    const float* Wq     = (const float*)d_in[1];
    const float* bq     = (const float*)d_in[2];
    const float* Wk     = (const float*)d_in[3];
    const float* bk     = (const float*)d_in[4];
    const float* w_vol  = (const float*)d_in[5];
    const float* b_vol  = (const float*)d_in[6];
    const float* w_volu = (const float*)d_in[7];
    const float* b_volu = (const float*)d_in[8];

    float* out_comp = (float*)d_out;                       // B*S*D
    float* out_bp   = out_comp + (size_t)BN * SN * DN;     // B*S
    float* out_rl   = out_bp + (size_t)BN * SN;            // 1

    int*   flags = (int*)d_ws;                             // B*S
    int*   pidx  = flags + (size_t)BN * SN;                // B*S
    int*   cnt   = pidx + (size_t)BN * SN;                 // B
    float* bsum  = (float*)(cnt + BN);                     // B
    unsigned char* Wfrag = (unsigned char*)(bsum + BN);    // 8*32768 = 262144 B
    unsigned char* Gfrag = Wfrag + 262144;                 // 8192 B

    k0_prep<<<32, 256, 0, stream>>>(Wq, Wk, w_vol, w_volu, Wfrag, Gfrag);

    const int lds_bytes = 2 * 32768 + 8192;                // 73728 B
    hipFuncSetAttribute((const void*)k1_mfma,
                        hipFuncAttributeMaxDynamicSharedMemorySize, lds_bytes);

    k1_mfma<<<dim3(SN / MBLK, BN), 256, lds_bytes, stream>>>(
        x, Wfrag, Gfrag, bq, bk, b_vol, b_volu, out_bp, flags);

    k2_scan<<<BN, 256, 0, stream>>>(flags, out_bp, pidx, cnt, bsum);

    k3_scatter<<<(BN * SN) / 4, 256, 0, stream>>>(x, pidx, out_comp);

    k3b_zerotail<<<(BN * SN) / 256, 256, 0, stream>>>(out_comp, cnt);

    k4_loss<<<1, 64, 0, stream>>>(bsum, out_rl);
}

// Round 5
// 118.387 us; speedup vs baseline: 5.6052x; 1.4732x over previous
//
#include <hip/hip_runtime.h>
#include <math.h>

#define BN 16
#define SN 8192
#define DN 256
#define MBLK 128
#define XROWS 129
#define EPSF 1e-8f

#define CHUNK_B 16384          // one W chunk: 16 cols x (q,k) frag-major
#define GATE_OFF (3 * CHUNK_B) // 49152
#define LDS_BYTES (XROWS * 512)// 66048 (x tile is the peak phase)

typedef __attribute__((ext_vector_type(8))) short short8;
typedef __attribute__((ext_vector_type(4))) float f32x4;

typedef const __attribute__((address_space(1))) unsigned int g_u32;
typedef __attribute__((address_space(3))) unsigned int l_u32;

__device__ __forceinline__ unsigned short f2bf(float f) {
    union { float f; unsigned int u; } cv; cv.f = f;
    unsigned int u = cv.u + 0x7FFFu + ((cv.u >> 16) & 1u);
    return (unsigned short)(u >> 16);
}

__device__ __forceinline__ void gload_lds16(const void* g, void* l) {
    __builtin_amdgcn_global_load_lds((g_u32*)g, (l_u32*)l, 16, 0, 0);
}

// ---------------------------------------------------------------------------
// k0: rewrite Wq/Wk into frag-major bf16 layout, 16 chunks x 16KB.
// Chunk ch = n>>4 holds cols [ch*16, ch*16+16) of BOTH mats:
//   byte = ch*16384 + (mat*8 + ks)*1024 + lane*16 + e*2,  lane = g*16 + (n&15)
// A ds_read_b128 of one fragment is base + lane*16 : linear, conflict-free.
// Gate tile (8KB): ks*1024 + lane*16 ; col0=w_vol, col1=w_volu, rest 0.
// ---------------------------------------------------------------------------
__global__ void k0_prep(const float* __restrict__ Wq, const float* __restrict__ Wk,
                        const float* __restrict__ w_vol, const float* __restrict__ w_volu,
                        unsigned char* __restrict__ Wfrag, unsigned char* __restrict__ Gfrag)
{
    const int tid = threadIdx.x;
    const int n   = blockIdx.x * 8 + (tid >> 5);   // 0..255
    const int k8  = tid & 31;                      // 8-elem group of K
    const int ch  = n >> 4;
    const int cc  = n & 15;
    const int ks  = k8 >> 2;
    const int g   = k8 & 3;

    short8 vq, vk;
    #pragma unroll
    for (int e = 0; e < 8; ++e) {
        const int k = k8 * 8 + e;
        vq[e] = (short)f2bf(Wq[(size_t)k * DN + n]);
        vk[e] = (short)f2bf(Wk[(size_t)k * DN + n]);
    }
    const size_t base = (size_t)ch * CHUNK_B + (size_t)((g * 16 + cc) * 16);
    *(short8*)(Wfrag + base + (size_t)(ks)     * 1024) = vq;
    *(short8*)(Wfrag + base + (size_t)(8 + ks) * 1024) = vk;

    if (blockIdx.x < 2) {
        const int gc = blockIdx.x * 8 + (tid >> 5);   // 0..15
        short8 vg;
        #pragma unroll
        for (int e = 0; e < 8; ++e) {
            const int k = k8 * 8 + e;
            float v = (gc == 0) ? w_vol[k] : ((gc == 1) ? w_volu[k] : 0.0f);
            vg[e] = (short)f2bf(v);
        }
        *(short8*)(Gfrag + (size_t)ks * 1024 + (size_t)((g * 16 + gc) * 16)) = vg;
    }
}

// ---------------------------------------------------------------------------
// k1: phase 1 — coalesced x staging -> swizzled LDS -> A-frags in registers.
//     phase 2 — reuse the x LDS region for W chunks (3-buffer, counted vmcnt).
// ---------------------------------------------------------------------------
__global__ __launch_bounds__(256, 2) void k1_mfma(
    const float* __restrict__ x,
    const unsigned char* __restrict__ Wfrag,
    const unsigned char* __restrict__ Gfrag,
    const float* __restrict__ bq, const float* __restrict__ bk,
    const float* __restrict__ b_vol, const float* __restrict__ b_volu,
    float* __restrict__ bp_out, int* __restrict__ flags)
{
    extern __shared__ unsigned char lds[];           // 66048 B

    const int tid = threadIdx.x;
    const int wm  = tid >> 6;
    const int l   = tid & 63;
    const int g   = l >> 4;
    const int c   = l & 15;
    const int b   = blockIdx.y;
    const int s0  = blockIdx.x * MBLK;

    // ---- phase 1: stage x rows s0-1 .. s0+127 coalesced, bf16, XOR-swizzled
    {
        unsigned short* xs = (unsigned short*)lds;
        const float* xb = x + (size_t)b * SN * DN;
        for (int f = tid; f < XROWS * 32; f += 256) {
            const int row = f >> 5, ch = f & 31;
            const int gs = s0 - 1 + row;
            float v[8];
            if (gs >= 0) {
                const float4* p = (const float4*)(xb + (size_t)gs * DN + ch * 8);
                float4 a = p[0], d = p[1];
                v[0] = a.x; v[1] = a.y; v[2] = a.z; v[3] = a.w;
                v[4] = d.x; v[5] = d.y; v[6] = d.z; v[7] = d.w;
            } else {
                #pragma unroll
                for (int i = 0; i < 8; ++i) v[i] = 0.0f;
            }
            short8 sv;
            #pragma unroll
            for (int i = 0; i < 8; ++i) sv[i] = (short)f2bf(v[i]);
            const int byte = row * 512 + ((ch * 16) ^ ((row & 7) << 4));
            *(short8*)((char*)xs + byte) = sv;
        }
    }
    __syncthreads();

    // ---- extract A fragments to registers (q window = k window + 1 row)
    short8 aq[2][8], ak[2][8];
    #pragma unroll
    for (int m = 0; m < 2; ++m) {
        const int rk = wm * 32 + m * 16 + c;
        const int rq = rk + 1;
        #pragma unroll
        for (int ks = 0; ks < 8; ++ks) {
            const int oq = rq * 512 + (((ks * 64) + g * 16) ^ ((rq & 7) << 4));
            const int ok = rk * 512 + (((ks * 64) + g * 16) ^ ((rk & 7) << 4));
            aq[m][ks] = *(const short8*)((const char*)lds + oq);
            ak[m][ks] = *(const short8*)((const char*)lds + ok);
        }
    }
    __syncthreads();   // all reads of the x tile complete; region now reusable

    // ---- preload biases (static-indexed registers)
    float bqv[16], bkv[16];
    #pragma unroll
    for (int i = 0; i < 16; ++i) { bqv[i] = bq[i * 16 + c]; bkv[i] = bk[i * 16 + c]; }

    // ---- phase 2 prologue: stage chunk0, gate, chunk1 (async)
    {
        #pragma unroll
        for (int j = 0; j < 4; ++j)
            gload_lds16(Wfrag + j * 4096 + tid * 16, lds + j * 4096 + wm * 1024);
        #pragma unroll
        for (int j = 0; j < 2; ++j)
            gload_lds16(Gfrag + j * 4096 + tid * 16, lds + GATE_OFF + j * 4096 + wm * 1024);
        #pragma unroll
        for (int j = 0; j < 4; ++j)
            gload_lds16(Wfrag + CHUNK_B + j * 4096 + tid * 16, lds + CHUNK_B + j * 4096 + wm * 1024);
    }
    asm volatile("s_waitcnt vmcnt(4)" ::: "memory");   // chunk0 + gate resident
    __builtin_amdgcn_s_barrier();

    float dt[2][4], nqv[2][4], nkv[2][4];
    #pragma unroll
    for (int m = 0; m < 2; ++m)
        #pragma unroll
        for (int r = 0; r < 4; ++r) { dt[m][r] = 0.f; nqv[m][r] = 0.f; nkv[m][r] = 0.f; }

    // ---- main loop: 16 chunks, 3-buffer pipeline, counted vmcnt
    #pragma unroll
    for (int i = 0; i < 16; ++i) {
        if (i + 2 <= 15) {
            const unsigned char* src = Wfrag + (size_t)(i + 2) * CHUNK_B;
            unsigned char* dst = lds + ((i + 2) % 3) * CHUNK_B;
            #pragma unroll
            for (int j = 0; j < 4; ++j)
                gload_lds16(src + j * 4096 + tid * 16, dst + j * 4096 + wm * 1024);
        }

        const unsigned char* bb = lds + (i % 3) * CHUNK_B;
        f32x4 cq[2], ck[2];
        cq[0] = (f32x4)(0.f); cq[1] = (f32x4)(0.f);
        ck[0] = (f32x4)(0.f); ck[1] = (f32x4)(0.f);
        #pragma unroll
        for (int ks = 0; ks < 8; ++ks) {
            const short8 bqf = *(const short8*)(bb + ks * 1024 + l * 16);
            const short8 bkf = *(const short8*)(bb + (8 + ks) * 1024 + l * 16);
            cq[0] = __builtin_amdgcn_mfma_f32_16x16x32_bf16(aq[0][ks], bqf, cq[0], 0, 0, 0);
            cq[1] = __builtin_amdgcn_mfma_f32_16x16x32_bf16(aq[1][ks], bqf, cq[1], 0, 0, 0);
            ck[0] = __builtin_amdgcn_mfma_f32_16x16x32_bf16(ak[0][ks], bkf, ck[0], 0, 0, 0);
            ck[1] = __builtin_amdgcn_mfma_f32_16x16x32_bf16(ak[1][ks], bkf, ck[1], 0, 0, 0);
        }

        #pragma unroll
        for (int m = 0; m < 2; ++m)
            #pragma unroll
            for (int r = 0; r < 4; ++r) {
                const float qv = cq[m][r] + bqv[i];
                const float kv = ck[m][r] + bkv[i];
                dt[m][r]  = fmaf(qv, kv, dt[m][r]);
                nqv[m][r] = fmaf(qv, qv, nqv[m][r]);
                nkv[m][r] = fmaf(kv, kv, nkv[m][r]);
            }

        // need chunk i+1 resident for next iter; chunk i+2's 4 loads may fly
        if (i + 2 <= 15) asm volatile("s_waitcnt vmcnt(4)" ::: "memory");
        else             asm volatile("s_waitcnt vmcnt(0)" ::: "memory");
        __builtin_amdgcn_s_barrier();
    }

    // ---- gates (16-col tile, col0=vol, col1=volu)
    f32x4 cg[2];
    cg[0] = (f32x4)(0.f); cg[1] = (f32x4)(0.f);
    #pragma unroll
    for (int ks = 0; ks < 8; ++ks) {
        const short8 bgf = *(const short8*)(lds + GATE_OFF + ks * 1024 + l * 16);
        cg[0] = __builtin_amdgcn_mfma_f32_16x16x32_bf16(aq[0][ks], bgf, cg[0], 0, 0, 0);
        cg[1] = __builtin_amdgcn_mfma_f32_16x16x32_bf16(aq[1][ks], bgf, cg[1], 0, 0, 0);
    }

    // ---- reduce over the 16 dim-lanes of each group
    #pragma unroll
    for (int m = 0; m < 2; ++m)
        #pragma unroll
        for (int r = 0; r < 4; ++r) {
            float a = dt[m][r], e = nqv[m][r], f = nkv[m][r];
            #pragma unroll
            for (int mask = 1; mask < 16; mask <<= 1) {
                a += __shfl_xor(a, mask);
                e += __shfl_xor(e, mask);
                f += __shfl_xor(f, mask);
            }
            dt[m][r] = a; nqv[m][r] = e; nkv[m][r] = f;
        }
    float vu_[2][4];
    #pragma unroll
    for (int m = 0; m < 2; ++m)
        #pragma unroll
        for (int r = 0; r < 4; ++r) vu_[m][r] = __shfl_xor(cg[m][r], 1);

    if (c == 0) {
        const float bv = b_vol[0], bu = b_volu[0];
        #pragma unroll
        for (int m = 0; m < 2; ++m)
            #pragma unroll
            for (int r = 0; r < 4; ++r) {
                const int s = s0 + wm * 32 + m * 16 + g * 4 + r;
                float comb;
                if (s == 0) comb = 1.0f;
                else {
                    float denom = fmaxf(sqrtf(nqv[m][r]), EPSF) * fmaxf(sqrtf(nkv[m][r]), EPSF);
                    float sim   = dt[m][r] / denom;
                    float vol   = 1.f / (1.f + expf(-(cg[m][r] + bv)));
                    float volu  = 1.f / (1.f + expf(-(vu_[m][r] + bu)));
                    comb = (1.f - sim) + 0.3f * vol + 0.2f * volu;
                }
                const float pbp = 1.f / (1.f + expf(-comb));
                const size_t o = (size_t)b * SN + s;
                bp_out[o] = pbp;
                flags[o]  = (pbp > 0.5f) ? 1 : 0;
            }
    }
}

// ---------------------------------------------------------------------------
// k2: per-batch scan of hard flags -> packed dest index, count, boundary sum
// ---------------------------------------------------------------------------
__global__ void k2_scan(const int* __restrict__ flags,
                        const float* __restrict__ bp,
                        int* __restrict__ pidx,
                        int* __restrict__ cnt,
                        float* __restrict__ bsum)
{
    const int b = blockIdx.x;
    const int t = threadIdx.x;
    __shared__ int   ssum[256];
    __shared__ float sf[256];

    const size_t base = (size_t)b * SN + (size_t)t * 32;
    int f[32];
    int run = 0;
    float fs = 0.f;
    #pragma unroll
    for (int i = 0; i < 32; ++i) {
        f[i] = flags[base + i];
        run += f[i];
        float p  = bp[base + i];
        float hf = (float)f[i];
        fs += hf + p - p;
    }
    ssum[t] = run;
    sf[t]   = fs;
    __syncthreads();

    for (int off = 1; off < 256; off <<= 1) {
        int v = (t >= off) ? ssum[t - off] : 0;
        __syncthreads();
        ssum[t] += v;
        __syncthreads();
    }
    const int incl = ssum[t];
    int running = incl - run;
    #pragma unroll
    for (int i = 0; i < 32; ++i) {
        running += f[i];
        pidx[base + i] = f[i] ? (running - 1) : -1;
    }
    if (t == 255) cnt[b] = incl;

    for (int off = 128; off > 0; off >>= 1) {
        if (t < off) sf[t] += sf[t + off];
        __syncthreads();
    }
    if (t == 0) bsum[b] = sf[0];
}

// ---------------------------------------------------------------------------
// k3: gather-copy hard rows; 4 rows per 256-thread block
// ---------------------------------------------------------------------------
__global__ void k3_scatter(const float* __restrict__ x,
                           const int* __restrict__ pidx,
                           float* __restrict__ out_comp)
{
    const int row  = blockIdx.x * 4 + (threadIdx.x >> 6);
    const int lane = threadIdx.x & 63;
    const int p = pidx[row];
    if (p < 0) return;
    const int b = row >> 13;
    const float4* src = (const float4*)(x + (size_t)row * DN);
    float4* dst = (float4*)(out_comp + ((size_t)b * SN + p) * DN);
    dst[lane] = src[lane];
}

// k3b: zero destination rows beyond each batch's boundary count
__global__ void k3b_zerotail(float* __restrict__ out_comp,
                             const int* __restrict__ cnt)
{
    const int gid = blockIdx.x * blockDim.x + threadIdx.x;
    const int b = gid >> 13;
    const int j = gid & (SN - 1);
    if (j >= cnt[b]) {
        float4* dst = (float4*)(out_comp + ((size_t)b * SN + j) * DN);
        const float4 z = make_float4(0.f, 0.f, 0.f, 0.f);
        for (int i = 0; i < DN / 4; ++i) dst[i] = z;
    }
}

// k4: ratio loss
__global__ void k4_loss(const float* __restrict__ bsum, float* __restrict__ out_rl)
{
    if (threadIdx.x == 0) {
        float acc = 0.f;
        for (int i = 0; i < BN; ++i) acc += bsum[i];
        float mean = acc / (float)BN;
        float d = mean - (float)(SN / 4);
        out_rl[0] = d * d;
    }
}

extern "C" void kernel_launch(void* const* d_in, const int* in_sizes, int n_in,
                              void* d_out, int out_size, void* d_ws, size_t ws_size,
                              hipStream_t stream) {
    const float* x      = (const float*)d_in[0];
    const float* Wq     = (const float*)d_in[1];
    const float* bq     = (const float*)d_in[2];
    const float* Wk     = (const float*)d_in[3];
    const float* bk     = (const float*)d_in[4];
    const float* w_vol  = (const float*)d_in[5];
    const float* b_vol  = (const float*)d_in[6];
    const float* w_volu = (const float*)d_in[7];
    const float* b_volu = (const float*)d_in[8];

    float* out_comp = (float*)d_out;                       // B*S*D
    float* out_bp   = out_comp + (size_t)BN * SN * DN;     // B*S
    float* out_rl   = out_bp + (size_t)BN * SN;            // 1

    int*   flags = (int*)d_ws;                             // B*S
    int*   pidx  = flags + (size_t)BN * SN;                // B*S
    int*   cnt   = pidx + (size_t)BN * SN;                 // B
    float* bsum  = (float*)(cnt + BN);                     // B
    unsigned char* Wfrag = (unsigned char*)(bsum + BN);    // 16*16384 = 262144 B
    unsigned char* Gfrag = Wfrag + 262144;                 // 8192 B

    k0_prep<<<32, 256, 0, stream>>>(Wq, Wk, w_vol, w_volu, Wfrag, Gfrag);

    hipFuncSetAttribute((const void*)k1_mfma,
                        hipFuncAttributeMaxDynamicSharedMemorySize, LDS_BYTES);

    k1_mfma<<<dim3(SN / MBLK, BN), 256, LDS_BYTES, stream>>>(
        x, Wfrag, Gfrag, bq, bk, b_vol, b_volu, out_bp, flags);

    k2_scan<<<BN, 256, 0, stream>>>(flags, out_bp, pidx, cnt, bsum);

    k3_scatter<<<(BN * SN) / 4, 256, 0, stream>>>(x, pidx, out_comp);

    k3b_zerotail<<<(BN * SN) / 256, 256, 0, stream>>>(out_comp, cnt);

    k4_loss<<<1, 64, 0, stream>>>(bsum, out_rl);
}